// Round 2
// baseline (223.840 us; speedup 1.0000x reference)
//
#include <hip/hip_runtime.h>
#include <math.h>

#define MU_PRIOR   0.6447f
#define LOGDET_SA  4.767705615349743f   /* 3*ln(4.9) */
#define INV_SA     (1.0f/4.9f)

__device__ __forceinline__ float warp_reduce_f(float v) {
#pragma unroll
    for (int off = 32; off > 0; off >>= 1) v += __shfl_down(v, off, 64);
    return v;
}

__device__ __forceinline__ double warp_reduce_d(double v) {
#pragma unroll
    for (int off = 32; off > 0; off >>= 1) v += __shfl_down(v, off, 64);
    return v;
}

// Each thread processes 4 consecutive rows -> all loads are aligned float4.
// Loads are batched into register arrays (2 phases) to maximize outstanding
// VMEM ops per wave; __launch_bounds__(256,2) allows up to 256 VGPRs.
__global__ __launch_bounds__(256, 2) void loss_main(
    const float* __restrict__ pred, const float* __restrict__ yobs,
    const float* __restrict__ rrs,  const float* __restrict__ rrsp,
    const float* __restrict__ nanarr, const float* __restrict__ cov,
    const float* __restrict__ mu, double* __restrict__ partial, int rows4)
{
    const int t = blockIdx.x * 256 + threadIdx.x;
    float acc = 0.0f;

    if (t < rows4) {
        const float4* Pp = reinterpret_cast<const float4*>(pred)   + (size_t)9 * t;
        const float4* Yp = reinterpret_cast<const float4*>(yobs)   + (size_t)9 * t;
        const float4* Np = reinterpret_cast<const float4*>(nanarr) + (size_t)9 * t;
        const float4* Rp = reinterpret_cast<const float4*>(rrs)    + (size_t)5 * t;
        const float4* Qp = reinterpret_cast<const float4*>(rrsp)   + (size_t)5 * t;
        const float4* Cp = reinterpret_cast<const float4*>(cov)    + (size_t)9 * t;
        const float4* Mp = reinterpret_cast<const float4*>(mu)     + (size_t)3 * t;

        // ================= Phase A: 27 independent float4 loads =============
        float4 Pv[9], Yv[9], Nv[9];
#pragma unroll
        for (int j = 0; j < 9; ++j) Pv[j] = Pp[j];
#pragma unroll
        for (int j = 0; j < 9; ++j) Yv[j] = Yp[j];
#pragma unroll
        for (int j = 0; j < 9; ++j) Nv[j] = Np[j];

        // ---- obs term: 10 * sum_r (sum_i dy^2) / lens_r ----
        float dy2[4]  = {0.f, 0.f, 0.f, 0.f};
        float lens[4] = {0.f, 0.f, 0.f, 0.f};
#pragma unroll
        for (int j = 0; j < 9; ++j) {
            const float pe[4] = {Pv[j].x, Pv[j].y, Pv[j].z, Pv[j].w};
            const float ye[4] = {Yv[j].x, Yv[j].y, Yv[j].z, Yv[j].w};
            const float ne[4] = {Nv[j].x, Nv[j].y, Nv[j].z, Nv[j].w};
#pragma unroll
            for (int k = 0; k < 4; ++k) {
                const int e = 4 * j + k;
                const int row = e / 9;              // compile-time after unroll
                const float d = pe[k] - ye[k];
                dy2[row]  += d * d;
                lens[row] += (ne[k] == ne[k]) ? 1.0f : 0.0f;  // !isnan
            }
        }
        acc += 10.0f * (dy2[0] / lens[0] + dy2[1] / lens[1] +
                        dy2[2] / lens[2] + dy2[3] / lens[3]);

        // ================= Phase B: 22 independent float4 loads =============
        float4 Rv[5], Qv[5], Cv[9], Mv[3];
#pragma unroll
        for (int j = 0; j < 5; ++j) Rv[j] = Rp[j];
#pragma unroll
        for (int j = 0; j < 5; ++j) Qv[j] = Qp[j];
#pragma unroll
        for (int j = 0; j < 9; ++j) Cv[j] = Cp[j];
#pragma unroll
        for (int j = 0; j < 3; ++j) Mv[j] = Mp[j];

        // ---- rrs term: sum dr^2 * w / 5 ----
        const float W[5] = {1.0f / (0.0015f * 0.0015f),
                            1.0f / (0.0012f * 0.0012f),
                            1.0f / (0.0010f * 0.0010f),
                            1.0f / (0.00086f * 0.00086f),
                            1.0f / (0.00057f * 0.00057f)};
        float racc = 0.f;
#pragma unroll
        for (int j = 0; j < 5; ++j) {
            const float re[4] = {Rv[j].x, Rv[j].y, Rv[j].z, Rv[j].w};
            const float qe[4] = {Qv[j].x, Qv[j].y, Qv[j].z, Qv[j].w};
#pragma unroll
            for (int k = 0; k < 4; ++k) {
                const int e = 4 * j + k;
                const int col = e % 5;              // compile-time after unroll
                const float d = re[k] - qe[k];
                racc += d * d * W[col];
            }
        }
        acc += racc * 0.2f;

        // ---- KL term: 0.5*(logdet_sa - log det(cov) + trace/4.9) per row ----
        float c[36];
#pragma unroll
        for (int j = 0; j < 9; ++j) {
            c[4*j] = Cv[j].x; c[4*j+1] = Cv[j].y; c[4*j+2] = Cv[j].z; c[4*j+3] = Cv[j].w;
        }
#pragma unroll
        for (int r = 0; r < 4; ++r) {
            const float* m = c + 9 * r;
            const float tr  = m[0] + m[4] + m[8];
            const float det = m[0] * (m[4]*m[8] - m[5]*m[7])
                            - m[1] * (m[3]*m[8] - m[5]*m[6])
                            + m[2] * (m[3]*m[7] - m[4]*m[6]);
            acc += 0.5f * (LOGDET_SA - __logf(det) + tr * INV_SA);
        }

        // ---- mu term: sum dm^2 / (4.9 * 6) ----
        float dmacc = 0.f;
#pragma unroll
        for (int j = 0; j < 3; ++j) {
            const float me[4] = {Mv[j].x, Mv[j].y, Mv[j].z, Mv[j].w};
#pragma unroll
            for (int k = 0; k < 4; ++k) {
                const float d = me[k] - MU_PRIOR;
                dmacc += d * d;
            }
        }
        acc += dmacc * (1.0f / 29.4f);
    }

    // block reduction -> double partial per block (deterministic, no atomics)
    acc = warp_reduce_f(acc);
    __shared__ float smem[4];
    const int lane = threadIdx.x & 63;
    const int wid  = threadIdx.x >> 6;
    if (lane == 0) smem[wid] = acc;
    __syncthreads();
    if (threadIdx.x == 0)
        partial[blockIdx.x] = (double)(smem[0] + smem[1] + smem[2] + smem[3]);
}

__global__ __launch_bounds__(256) void loss_final(
    const double* __restrict__ partial, int nblocks,
    const float* __restrict__ params, int nparams,
    const float* __restrict__ pred, const float* __restrict__ yobs,
    const float* __restrict__ rrs,  const float* __restrict__ rrsp,
    const float* __restrict__ nanarr, const float* __restrict__ cov,
    const float* __restrict__ mu, int rows, float* __restrict__ out)
{
    const int rows4 = rows >> 2;
    double accA = 0.0;   // per-row total (un-normalized)
    double accB = 0.0;   // l2 over parameters (un-normalized)

    for (int i = threadIdx.x; i < nblocks; i += 256) accA += partial[i];
    for (int i = threadIdx.x; i < nparams; i += 256) {
        const float d = params[i] - 1.0f;
        accB += (double)(d * d);
    }

    // tail rows (rows % 4) handled scalar here (dead for N=1e6)
    const int r = rows4 * 4 + (int)threadIdx.x;
    if (r < rows) {
        float dy2 = 0.f, len = 0.f;
        for (int i = 0; i < 9; ++i) {
            const float d = pred[9*r + i] - yobs[9*r + i];
            dy2 += d * d;
            const float v = nanarr[9*r + i];
            len += (v == v) ? 1.f : 0.f;
        }
        const float W[5] = {1.0f / (0.0015f * 0.0015f),
                            1.0f / (0.0012f * 0.0012f),
                            1.0f / (0.0010f * 0.0010f),
                            1.0f / (0.00086f * 0.00086f),
                            1.0f / (0.00057f * 0.00057f)};
        float racc = 0.f;
        for (int i = 0; i < 5; ++i) {
            const float d = rrs[5*r + i] - rrsp[5*r + i];
            racc += d * d * W[i];
        }
        const float* m = cov + 9 * (size_t)r;
        const float tr  = m[0] + m[4] + m[8];
        const float det = m[0] * (m[4]*m[8] - m[5]*m[7])
                        - m[1] * (m[3]*m[8] - m[5]*m[6])
                        + m[2] * (m[3]*m[7] - m[4]*m[6]);
        float dm = 0.f;
        for (int i = 0; i < 3; ++i) {
            const float d = mu[3*r + i] - MU_PRIOR;
            dm += d * d;
        }
        accA += (double)(racc * 0.2f + 10.f * dy2 / len
                         + 0.5f * (LOGDET_SA - __logf(det) + tr * INV_SA)
                         + dm * (1.f / 29.4f));
    }

    double val = accA * (1.0 / (double)rows) + accB * (1.0 / (double)nparams);
    val = warp_reduce_d(val);
    __shared__ double sm[4];
    const int lane = threadIdx.x & 63;
    const int wid  = threadIdx.x >> 6;
    if (lane == 0) sm[wid] = val;
    __syncthreads();
    if (threadIdx.x == 0)
        out[0] = (float)(sm[0] + sm[1] + sm[2] + sm[3]);
}

extern "C" void kernel_launch(void* const* d_in, const int* in_sizes, int n_in,
                              void* d_out, int out_size, void* d_ws, size_t ws_size,
                              hipStream_t stream) {
    const float* pred   = (const float*)d_in[0];
    const float* yobs   = (const float*)d_in[1];
    const float* rrs    = (const float*)d_in[2];
    const float* rrsp   = (const float*)d_in[3];
    const float* nanarr = (const float*)d_in[4];
    const float* cov    = (const float*)d_in[5];
    const float* mu     = (const float*)d_in[6];
    const float* params = (const float*)d_in[7];
    float* out = (float*)d_out;

    const int rows  = in_sizes[0] / 9;
    const int rows4 = rows / 4;
    int nblocks = (rows4 + 255) / 256;
    if (nblocks < 1) nblocks = 1;

    double* partial = (double*)d_ws;   // nblocks doubles; every entry written each call

    loss_main<<<nblocks, 256, 0, stream>>>(pred, yobs, rrs, rrsp, nanarr, cov, mu,
                                           partial, rows4);
    loss_final<<<1, 256, 0, stream>>>(partial, nblocks, params, in_sizes[7],
                                      pred, yobs, rrs, rrsp, nanarr, cov, mu,
                                      rows, out);
}

// Round 5
// 209.537 us; speedup vs baseline: 1.0683x; 1.0683x over previous
//
#include <hip/hip_runtime.h>
#include <math.h>

#define MU_PRIOR   0.6447f
#define LOGDET_SA  4.767705615349743f   /* 3*ln(4.9) */
#define INV_SA     (1.0f/4.9f)

#define CHUNK  256              /* rows per block (== block size: 1 row/thread) */
#define NF4_9  576              /* CHUNK*9/4 float4 per 9-wide array */
#define NF4_5  320              /* CHUNK*5/4 */
#define NF4_3  192              /* CHUNK*3/4 */

#define W0 (1.0f / (0.0015f  * 0.0015f))
#define W1 (1.0f / (0.0012f  * 0.0012f))
#define W2 (1.0f / (0.0010f  * 0.0010f))
#define W3 (1.0f / (0.00086f * 0.00086f))
#define W4 (1.0f / (0.00057f * 0.00057f))

__device__ __forceinline__ float warp_reduce_f(float v) {
#pragma unroll
    for (int off = 32; off > 0; off >>= 1) v += __shfl_down(v, off, 64);
    return v;
}

__device__ __forceinline__ double warp_reduce_d(double v) {
#pragma unroll
    for (int off = 32; off > 0; off >>= 1) v += __shfl_down(v, off, 64);
    return v;
}

// Block = 256 threads = 256 rows. Row-coupled arrays (pred/yobs/nan/cov) are
// staged to LDS with coalesced float4 loads + ds_write_b128 (plain,
// well-defined semantics; total static LDS 36,880 B < 64 KB cap).
// Separable terms (rrs, mu) are consumed directly from coalesced loads.
__global__ __launch_bounds__(256) void loss_main(
    const float* __restrict__ pred, const float* __restrict__ yobs,
    const float* __restrict__ rrs,  const float* __restrict__ rrsp,
    const float* __restrict__ nanarr, const float* __restrict__ cov,
    const float* __restrict__ mu, double* __restrict__ partial)
{
    __shared__ float4 sP[NF4_9], sY[NF4_9], sN[NF4_9], sC[NF4_9];

    const int tid = threadIdx.x;
    const size_t rowBase = (size_t)blockIdx.x * CHUNK;

    const float4* gP = reinterpret_cast<const float4*>(pred   + rowBase * 9);
    const float4* gY = reinterpret_cast<const float4*>(yobs   + rowBase * 9);
    const float4* gN = reinterpret_cast<const float4*>(nanarr + rowBase * 9);
    const float4* gC = reinterpret_cast<const float4*>(cov    + rowBase * 9);
    const float4* gR = reinterpret_cast<const float4*>(rrs    + rowBase * 5);
    const float4* gQ = reinterpret_cast<const float4*>(rrsp   + rowBase * 5);
    const float4* gM = reinterpret_cast<const float4*>(mu     + rowBase * 3);

    // ---- coalesced staging: NF4_9 = 2.25 * 256 -> 2 full strides + 1/4 ----
    {
        const float4 p0 = gP[tid], p1 = gP[tid + 256];
        const float4 y0 = gY[tid], y1 = gY[tid + 256];
        const float4 n0 = gN[tid], n1 = gN[tid + 256];
        const float4 c0 = gC[tid], c1 = gC[tid + 256];
        sP[tid] = p0; sP[tid + 256] = p1;
        sY[tid] = y0; sY[tid + 256] = y1;
        sN[tid] = n0; sN[tid + 256] = n1;
        sC[tid] = c0; sC[tid + 256] = c1;
        if (tid < NF4_9 - 512) {   // tid < 64
            sP[tid + 512] = gP[tid + 512];
            sY[tid + 512] = gY[tid + 512];
            sN[tid + 512] = gN[tid + 512];
            sC[tid + 512] = gC[tid + 512];
        }
    }

    float acc = 0.0f;

    // ---- rrs term (separable): coalesced float4, rotating weight window ----
    // element e = 4*i + k (i = tid + 256*j) has col = e % 5.
    // ew[k] = W[(4*tid + k) % 5]; col(e) = (4*tid - j + k) mod 5.
    {
        const int w0 = (5 - (tid % 5)) % 5;   // (4*tid) % 5
        float ew[5];
#pragma unroll
        for (int k = 0; k < 5; ++k) {
            int idx = w0 + k; if (idx >= 5) idx -= 5;
            ew[k] = (idx == 0) ? W0 : (idx == 1) ? W1 : (idx == 2) ? W2
                   : (idx == 3) ? W3 : W4;
        }
        float racc = 0.f;
#pragma unroll
        for (int j = 0; j < 2; ++j) {          // NF4_5 = 320 -> 1.25 strides
            const int i = tid + 256 * j;
            if (j == 0 || i < NF4_5) {
                const float4 r = gR[i];
                const float4 q = gQ[i];
                const int k0 = (5 - j) % 5;    // compile-time after unroll
                const float d0 = r.x - q.x, d1 = r.y - q.y;
                const float d2 = r.z - q.z, d3 = r.w - q.w;
                racc += d0 * d0 * ew[(k0    ) % 5];
                racc += d1 * d1 * ew[(k0 + 1) % 5];
                racc += d2 * d2 * ew[(k0 + 2) % 5];
                racc += d3 * d3 * ew[(k0 + 3) % 5];
            }
        }
        acc += racc * 0.2f;
    }

    // ---- mu term (separable): coalesced float4, NF4_3 = 192 < 256 ----
    if (tid < NF4_3) {
        const float4 v = gM[tid];
        const float d0 = v.x - MU_PRIOR, d1 = v.y - MU_PRIOR;
        const float d2 = v.z - MU_PRIOR, d3 = v.w - MU_PRIOR;
        acc += (d0 * d0 + d1 * d1 + d2 * d2 + d3 * d3) * (1.0f / 29.4f);
    }

    __syncthreads();

    // ---- per-row terms from LDS: row = tid; 36 B/lane stride -> 2-way bank
    //      aliasing across 64 lanes (free per m136) ----
    {
        const float* p = reinterpret_cast<const float*>(sP) + 9 * tid;
        const float* y = reinterpret_cast<const float*>(sY) + 9 * tid;
        const float* a = reinterpret_cast<const float*>(sN) + 9 * tid;
        const float* m = reinterpret_cast<const float*>(sC) + 9 * tid;

        float dy2 = 0.f, len = 0.f;
#pragma unroll
        for (int k = 0; k < 9; ++k) {
            const float d = p[k] - y[k];
            dy2 += d * d;
            const float v = a[k];
            len += (v == v) ? 1.0f : 0.0f;
        }
        acc += 10.0f * dy2 / len;

        const float tr  = m[0] + m[4] + m[8];
        const float det = m[0] * (m[4] * m[8] - m[5] * m[7])
                        - m[1] * (m[3] * m[8] - m[5] * m[6])
                        + m[2] * (m[3] * m[7] - m[4] * m[6]);
        acc += 0.5f * (LOGDET_SA - __logf(det) + tr * INV_SA);
    }

    // ---- block reduction -> double partial (deterministic, no atomics) ----
    acc = warp_reduce_f(acc);
    __shared__ float smem[4];
    const int lane = tid & 63;
    const int wid  = tid >> 6;
    if (lane == 0) smem[wid] = acc;
    __syncthreads();
    if (tid == 0)
        partial[blockIdx.x] = (double)(smem[0] + smem[1] + smem[2] + smem[3]);
}

__global__ __launch_bounds__(256) void loss_final(
    const double* __restrict__ partial, int nblocks,
    const float* __restrict__ params, int nparams,
    const float* __restrict__ pred, const float* __restrict__ yobs,
    const float* __restrict__ rrs,  const float* __restrict__ rrsp,
    const float* __restrict__ nanarr, const float* __restrict__ cov,
    const float* __restrict__ mu, int rows, float* __restrict__ out)
{
    const int mainRows = nblocks * CHUNK;
    double accA = 0.0;   // per-row total (un-normalized)
    double accB = 0.0;   // l2 over parameters (un-normalized)

    for (int i = threadIdx.x; i < nblocks; i += 256) accA += partial[i];
    for (int i = threadIdx.x; i < nparams; i += 256) {
        const float d = params[i] - 1.0f;
        accB += (double)(d * d);
    }

    // tail rows (rows % CHUNK), scalar loads (tiny)
    for (int r = mainRows + (int)threadIdx.x; r < rows; r += 256) {
        float dy2 = 0.f, len = 0.f;
        for (int i = 0; i < 9; ++i) {
            const float d = pred[9 * (size_t)r + i] - yobs[9 * (size_t)r + i];
            dy2 += d * d;
            const float v = nanarr[9 * (size_t)r + i];
            len += (v == v) ? 1.f : 0.f;
        }
        const float W[5] = {W0, W1, W2, W3, W4};
        float racc = 0.f;
        for (int i = 0; i < 5; ++i) {
            const float d = rrs[5 * (size_t)r + i] - rrsp[5 * (size_t)r + i];
            racc += d * d * W[i];
        }
        const float* m = cov + 9 * (size_t)r;
        const float tr  = m[0] + m[4] + m[8];
        const float det = m[0] * (m[4] * m[8] - m[5] * m[7])
                        - m[1] * (m[3] * m[8] - m[5] * m[6])
                        + m[2] * (m[3] * m[7] - m[4] * m[6]);
        float dm = 0.f;
        for (int i = 0; i < 3; ++i) {
            const float d = mu[3 * (size_t)r + i] - MU_PRIOR;
            dm += d * d;
        }
        accA += (double)(racc * 0.2f + 10.f * dy2 / len
                         + 0.5f * (LOGDET_SA - __logf(det) + tr * INV_SA)
                         + dm * (1.f / 29.4f));
    }

    double val = accA * (1.0 / (double)rows) + accB * (1.0 / (double)nparams);
    val = warp_reduce_d(val);
    __shared__ double sm[4];
    const int lane = threadIdx.x & 63;
    const int wid  = threadIdx.x >> 6;
    if (lane == 0) sm[wid] = val;
    __syncthreads();
    if (threadIdx.x == 0)
        out[0] = (float)(sm[0] + sm[1] + sm[2] + sm[3]);
}

extern "C" void kernel_launch(void* const* d_in, const int* in_sizes, int n_in,
                              void* d_out, int out_size, void* d_ws, size_t ws_size,
                              hipStream_t stream) {
    const float* pred   = (const float*)d_in[0];
    const float* yobs   = (const float*)d_in[1];
    const float* rrs    = (const float*)d_in[2];
    const float* rrsp   = (const float*)d_in[3];
    const float* nanarr = (const float*)d_in[4];
    const float* cov    = (const float*)d_in[5];
    const float* mu     = (const float*)d_in[6];
    const float* params = (const float*)d_in[7];
    float* out = (float*)d_out;

    const int rows    = in_sizes[0] / 9;
    const int nblocks = rows / CHUNK;          // full chunks; tail in loss_final

    double* partial = (double*)d_ws;           // nblocks doubles, all written

    if (nblocks > 0)
        loss_main<<<nblocks, 256, 0, stream>>>(pred, yobs, rrs, rrsp, nanarr,
                                               cov, mu, partial);
    loss_final<<<1, 256, 0, stream>>>(partial, nblocks, params, in_sizes[7],
                                      pred, yobs, rrs, rrsp, nanarr, cov, mu,
                                      rows, out);
}

// Round 7
// 208.197 us; speedup vs baseline: 1.0751x; 1.0064x over previous
//
#include <hip/hip_runtime.h>
#include <math.h>

#define MU_PRIOR   0.6447f
#define LOGDET_SA  4.767705615349743f   /* 3*ln(4.9) */
#define INV_SA     (1.0f/4.9f)

#define CW      64              /* rows per wave-chunk (1 row/lane in compute) */
#define NF4C    144             /* CW*9/4 float4 per 9-wide array per chunk */
#define NF4R    80              /* CW*5/4 */
#define NF4M    48              /* CW*3/4 */
#define GRID    2048            /* persistent blocks (8/CU nominal) */

#define W0 (1.0f / (0.0015f  * 0.0015f))
#define W1 (1.0f / (0.0012f  * 0.0012f))
#define W2 (1.0f / (0.0010f  * 0.0010f))
#define W3 (1.0f / (0.00086f * 0.00086f))
#define W4 (1.0f / (0.00057f * 0.00057f))

__device__ __forceinline__ float warp_reduce_f(float v) {
#pragma unroll
    for (int off = 32; off > 0; off >>= 1) v += __shfl_down(v, off, 64);
    return v;
}

__device__ __forceinline__ double warp_reduce_d(double v) {
#pragma unroll
    for (int off = 32; off > 0; off >>= 1) v += __shfl_down(v, off, 64);
    return v;
}

// pack (pred-yobs)^2 with nan-flag in the sign bit (d2 >= 0 always)
__device__ __forceinline__ float comb1(float p, float y, float n) {
    const float d = p - y;
    const float d2 = d * d;
    const unsigned u = __float_as_uint(d2) | ((n == n) ? 0u : 0x80000000u);
    return __uint_as_float(u);
}
__device__ __forceinline__ float4 comb4(float4 p, float4 y, float4 n) {
    float4 o;
    o.x = comb1(p.x, y.x, n.x); o.y = comb1(p.y, y.y, n.y);
    o.z = comb1(p.z, y.z, n.z); o.w = comb1(p.w, y.w, n.w);
    return o;
}

// Persistent blocks; each of the 4 waves independently grid-strides over
// 64-row chunks with a private LDS slice. NO __syncthreads in the loop:
// same-wave LDS exchange is ordered by lgkmcnt (lockstep SIMD), pinned with
// wave_barrier. Latency hidden by many independent waves per CU.
__global__ __launch_bounds__(256) void loss_main(
    const float* __restrict__ pred, const float* __restrict__ yobs,
    const float* __restrict__ rrs,  const float* __restrict__ rrsp,
    const float* __restrict__ nanarr, const float* __restrict__ cov,
    const float* __restrict__ mu, double* __restrict__ partial, int nchunks)
{
    __shared__ float4 sV[4 * NF4C];   // packed d2|nanflag, per-wave slices
    __shared__ float4 sC[4 * NF4C];   // cov, per-wave slices

    const int tid  = threadIdx.x;
    const int lane = tid & 63;
    const int wid  = tid >> 6;
    const int wslot = wid * NF4C;                 // this wave's float4 offset
    const int wgid  = blockIdx.x * 4 + wid;       // global wave id
    const int nw    = (int)gridDim.x * 4;

    // per-lane rotated rrs weights: ew[k] = W[(4*lane + k) % 5]
    const int w0 = (5 - (lane % 5)) % 5;
    float ew[5];
#pragma unroll
    for (int k = 0; k < 5; ++k) {
        int idx = w0 + k; if (idx >= 5) idx -= 5;
        ew[k] = (idx == 0) ? W0 : (idx == 1) ? W1 : (idx == 2) ? W2
               : (idx == 3) ? W3 : W4;
    }

    float acc = 0.0f;

    for (int c = wgid; c < nchunks; c += nw) {
        const float4* gP = reinterpret_cast<const float4*>(pred)   + (size_t)c * NF4C;
        const float4* gY = reinterpret_cast<const float4*>(yobs)   + (size_t)c * NF4C;
        const float4* gN = reinterpret_cast<const float4*>(nanarr) + (size_t)c * NF4C;
        const float4* gC = reinterpret_cast<const float4*>(cov)    + (size_t)c * NF4C;
        const float4* gR = reinterpret_cast<const float4*>(rrs)    + (size_t)c * NF4R;
        const float4* gQ = reinterpret_cast<const float4*>(rrsp)   + (size_t)c * NF4R;
        const float4* gM = reinterpret_cast<const float4*>(mu)     + (size_t)c * NF4M;

        // ---- issue all loads (coalesced float4, lane-contiguous) ----
        const float4 p0 = gP[lane], p1 = gP[lane + 64];
        const float4 y0 = gY[lane], y1 = gY[lane + 64];
        const float4 n0 = gN[lane], n1 = gN[lane + 64];
        const float4 c0 = gC[lane], c1 = gC[lane + 64];
        const float4 r0 = gR[lane], q0 = gQ[lane];
        float4 p2, y2, n2, c2, r1, q1, m0;
        if (lane < 16) {
            p2 = gP[lane + 128]; y2 = gY[lane + 128];
            n2 = gN[lane + 128]; c2 = gC[lane + 128];
            r1 = gR[lane + 64];  q1 = gQ[lane + 64];
        }
        if (lane < 48) m0 = gM[lane];

        // ---- rrs term from registers (chunk base ≡ 0 mod 5; i=lane+64
        //      rotates cols by +1 since 256 ≡ 1 mod 5) ----
        {
            float ra = 0.f;
            const float d0 = r0.x - q0.x, d1 = r0.y - q0.y;
            const float d2 = r0.z - q0.z, d3 = r0.w - q0.w;
            ra += d0 * d0 * ew[0] + d1 * d1 * ew[1]
                + d2 * d2 * ew[2] + d3 * d3 * ew[3];
            if (lane < 16) {
                const float e0 = r1.x - q1.x, e1 = r1.y - q1.y;
                const float e2 = r1.z - q1.z, e3 = r1.w - q1.w;
                ra += e0 * e0 * ew[1] + e1 * e1 * ew[2]
                    + e2 * e2 * ew[3] + e3 * e3 * ew[4];
            }
            acc += ra * 0.2f;
        }

        // ---- mu term from registers ----
        if (lane < 48) {
            const float d0 = m0.x - MU_PRIOR, d1 = m0.y - MU_PRIOR;
            const float d2 = m0.z - MU_PRIOR, d3 = m0.w - MU_PRIOR;
            acc += (d0 * d0 + d1 * d1 + d2 * d2 + d3 * d3) * (1.0f / 29.4f);
        }

        // ---- stage packed V and C into this wave's private LDS slice ----
        sV[wslot + lane]       = comb4(p0, y0, n0);
        sV[wslot + lane + 64]  = comb4(p1, y1, n1);
        sC[wslot + lane]       = c0;
        sC[wslot + lane + 64]  = c1;
        if (lane < 16) {
            sV[wslot + lane + 128] = comb4(p2, y2, n2);
            sC[wslot + lane + 128] = c2;
        }

        __builtin_amdgcn_wave_barrier();   // pin order; lgkmcnt handles data

        // ---- per-row terms: row = lane (9-float stride -> 2-way bank, free)
        {
            const float* v = reinterpret_cast<const float*>(sV + wslot) + 9 * lane;
            const float* m = reinterpret_cast<const float*>(sC + wslot) + 9 * lane;
            float dy2 = 0.f, len = 0.f;
#pragma unroll
            for (int k = 0; k < 9; ++k) {
                const unsigned u = __float_as_uint(v[k]);
                dy2 += __uint_as_float(u & 0x7fffffffu);
                len += (float)(1u - (u >> 31));
            }
            acc += 10.0f * dy2 / len;

            const float tr  = m[0] + m[4] + m[8];
            const float det = m[0] * (m[4] * m[8] - m[5] * m[7])
                            - m[1] * (m[3] * m[8] - m[5] * m[6])
                            + m[2] * (m[3] * m[7] - m[4] * m[6]);
            acc += 0.5f * (LOGDET_SA - __logf(det) + tr * INV_SA);
        }

        __builtin_amdgcn_wave_barrier();   // slice reuse next iter: keep order
    }

    // ---- block reduction -> double partial (once per block) ----
    acc = warp_reduce_f(acc);
    __shared__ float smem[4];
    if (lane == 0) smem[wid] = acc;
    __syncthreads();
    if (tid == 0)
        partial[blockIdx.x] = (double)(smem[0] + smem[1] + smem[2] + smem[3]);
}

__global__ __launch_bounds__(256) void loss_final(
    const double* __restrict__ partial, int npartials,
    const float* __restrict__ params, int nparams,
    const float* __restrict__ pred, const float* __restrict__ yobs,
    const float* __restrict__ rrs,  const float* __restrict__ rrsp,
    const float* __restrict__ nanarr, const float* __restrict__ cov,
    const float* __restrict__ mu, int mainRows, int rows,
    float* __restrict__ out)
{
    double accA = 0.0;   // per-row total (un-normalized)
    double accB = 0.0;   // l2 over parameters (un-normalized)

    for (int i = threadIdx.x; i < npartials; i += 256) accA += partial[i];
    for (int i = threadIdx.x; i < nparams; i += 256) {
        const float d = params[i] - 1.0f;
        accB += (double)(d * d);
    }

    // tail rows (rows % CW), scalar loads (zero iterations for N=1e6)
    for (int r = mainRows + (int)threadIdx.x; r < rows; r += 256) {
        float dy2 = 0.f, len = 0.f;
        for (int i = 0; i < 9; ++i) {
            const float d = pred[9 * (size_t)r + i] - yobs[9 * (size_t)r + i];
            dy2 += d * d;
            const float v = nanarr[9 * (size_t)r + i];
            len += (v == v) ? 1.f : 0.f;
        }
        const float W[5] = {W0, W1, W2, W3, W4};
        float racc = 0.f;
        for (int i = 0; i < 5; ++i) {
            const float d = rrs[5 * (size_t)r + i] - rrsp[5 * (size_t)r + i];
            racc += d * d * W[i];
        }
        const float* m = cov + 9 * (size_t)r;
        const float tr  = m[0] + m[4] + m[8];
        const float det = m[0] * (m[4] * m[8] - m[5] * m[7])
                        - m[1] * (m[3] * m[8] - m[5] * m[6])
                        + m[2] * (m[3] * m[7] - m[4] * m[6]);
        float dm = 0.f;
        for (int i = 0; i < 3; ++i) {
            const float d = mu[3 * (size_t)r + i] - MU_PRIOR;
            dm += d * d;
        }
        accA += (double)(racc * 0.2f + 10.f * dy2 / len
                         + 0.5f * (LOGDET_SA - __logf(det) + tr * INV_SA)
                         + dm * (1.f / 29.4f));
    }

    double val = accA * (1.0 / (double)rows) + accB * (1.0 / (double)nparams);
    val = warp_reduce_d(val);
    __shared__ double sm[4];
    const int lane = threadIdx.x & 63;
    const int wid  = threadIdx.x >> 6;
    if (lane == 0) sm[wid] = val;
    __syncthreads();
    if (threadIdx.x == 0)
        out[0] = (float)(sm[0] + sm[1] + sm[2] + sm[3]);
}

extern "C" void kernel_launch(void* const* d_in, const int* in_sizes, int n_in,
                              void* d_out, int out_size, void* d_ws, size_t ws_size,
                              hipStream_t stream) {
    const float* pred   = (const float*)d_in[0];
    const float* yobs   = (const float*)d_in[1];
    const float* rrs    = (const float*)d_in[2];
    const float* rrsp   = (const float*)d_in[3];
    const float* nanarr = (const float*)d_in[4];
    const float* cov    = (const float*)d_in[5];
    const float* mu     = (const float*)d_in[6];
    const float* params = (const float*)d_in[7];
    float* out = (float*)d_out;

    const int rows     = in_sizes[0] / 9;
    const int nchunks  = rows / CW;          // 15,625 for N=1e6 (exact)
    const int mainRows = nchunks * CW;
    int grid = (nchunks * 4 < GRID * 4) ? ((nchunks + 3) / 4 > 0 ? (nchunks + 3) / 4 : 1) : GRID;
    if (grid > GRID) grid = GRID;

    double* partial = (double*)d_ws;   // `grid` doubles, all written every call

    loss_main<<<grid, 256, 0, stream>>>(pred, yobs, rrs, rrsp, nanarr,
                                        cov, mu, partial, nchunks);
    loss_final<<<1, 256, 0, stream>>>(partial, grid, params, in_sizes[7],
                                      pred, yobs, rrs, rrsp, nanarr, cov, mu,
                                      mainRows, rows, out);
}